// Round 1
// baseline (3136.380 us; speedup 1.0000x reference)
//
#include <hip/hip_runtime.h>
#include <hip/hip_bf16.h>
#include <math.h>

// Sizes (fixed for this problem)
#define NROW   4096
#define DPROJ  1024
#define LDH    1360          // 1024 + 256 + 64 + 16
#define NB_H   313           // ceil(20003/64)
#define NB_T   157           // ceil(10000/64)

// ---------------------------------------------------------------------------
// Kernel 1: H = hidden @ [proj0 | proj1 | proj2 | proj3]   (fp32, 64x64 tile)
// ---------------------------------------------------------------------------
__global__ void pals_proj_gemm(const float* __restrict__ hidden,
                               const float* __restrict__ p0,
                               const float* __restrict__ p1,
                               const float* __restrict__ p2,
                               const float* __restrict__ p3,
                               float* __restrict__ H) {
    __shared__ __align__(16) float As[16][68];
    __shared__ __align__(16) float Bs[16][68];
    const int tx = threadIdx.x & 15, ty = threadIdx.x >> 4;
    const int rb = blockIdx.y * 64, cb = blockIdx.x * 64;
    float acc[4][4] = {};
    for (int k0 = 0; k0 < DPROJ; k0 += 16) {
        {   // A tile: 64 rows x 16 k (transposed store)
            int r  = threadIdx.x >> 2;
            int kq = (threadIdx.x & 3) * 4;
            float4 a = *(const float4*)(hidden + (size_t)(rb + r) * DPROJ + k0 + kq);
            As[kq + 0][r] = a.x; As[kq + 1][r] = a.y;
            As[kq + 2][r] = a.z; As[kq + 3][r] = a.w;
        }
        {   // B tile: 16 k x 64 cols (proj matrices are [K][d_i] row-major)
            int kk = threadIdx.x >> 4;
            int m4 = (threadIdx.x & 15) * 4;
            int k  = k0 + kk;
            for (int j = 0; j < 4; ++j) {
                int c = cb + m4 + j;
                float v = 0.f;
                if      (c < 1024) v = p0[(size_t)k * 1024 + c];
                else if (c < 1280) v = p1[(size_t)k * 256  + (c - 1024)];
                else if (c < 1344) v = p2[(size_t)k * 64   + (c - 1280)];
                else if (c < 1360) v = p3[(size_t)k * 16   + (c - 1344)];
                Bs[kk][m4 + j] = v;
            }
        }
        __syncthreads();
        #pragma unroll
        for (int k = 0; k < 16; ++k) {
            float4 a = *(const float4*)&As[k][ty * 4];
            float4 b = *(const float4*)&Bs[k][tx * 4];
            float av[4] = {a.x, a.y, a.z, a.w};
            float bv[4] = {b.x, b.y, b.z, b.w};
            #pragma unroll
            for (int i = 0; i < 4; ++i)
                #pragma unroll
                for (int j = 0; j < 4; ++j)
                    acc[i][j] += av[i] * bv[j];
        }
        __syncthreads();
    }
    for (int i = 0; i < 4; ++i) {
        int r = rb + ty * 4 + i;
        for (int j = 0; j < 4; ++j) {
            int c = cb + tx * 4 + j;
            if (c < LDH) H[(size_t)r * LDH + c] = acc[i][j];
        }
    }
}

// ---------------------------------------------------------------------------
// Kernel 2: logits tile (A = H[:, hoff:hoff+K], B^T = W rows) + per-row
// partial sum of exp(logit + bias). Deterministic partials per col-block.
// W covers rows [0, split); Wx covers [split, vocab) (cluster straddle).
// ---------------------------------------------------------------------------
__global__ void pals_logits_sumexp(const float* __restrict__ H, int hoff, int K,
                                   const float* __restrict__ W,
                                   const float* __restrict__ Wx,
                                   const float* __restrict__ bias,
                                   const float* __restrict__ biasx,
                                   int split, int vocab,
                                   float* __restrict__ partial, int nCB) {
    __shared__ __align__(16) float As[16][68];
    __shared__ __align__(16) float Ws[16][68];
    __shared__ float red[16][64];
    const int tx = threadIdx.x & 15, ty = threadIdx.x >> 4;
    const int rb = blockIdx.y * 64, cb = blockIdx.x * 64;
    float acc[4][4] = {};
    for (int k0 = 0; k0 < K; k0 += 16) {
        {   // A tile (H rows, K contiguous)
            int r  = threadIdx.x >> 2;
            int kq = (threadIdx.x & 3) * 4;
            float4 a = *(const float4*)(H + (size_t)(rb + r) * LDH + hoff + k0 + kq);
            As[kq + 0][r] = a.x; As[kq + 1][r] = a.y;
            As[kq + 2][r] = a.z; As[kq + 3][r] = a.w;
        }
        {   // W tile: rows are vocab entries, K contiguous (NT gemm)
            int r  = threadIdx.x >> 2;
            int kq = (threadIdx.x & 3) * 4;
            int gc = cb + r;
            float4 wv = make_float4(0.f, 0.f, 0.f, 0.f);
            if (gc < split)      wv = *(const float4*)(W  + (size_t)gc * K + k0 + kq);
            else if (gc < vocab) wv = *(const float4*)(Wx + (size_t)(gc - split) * K + k0 + kq);
            Ws[kq + 0][r] = wv.x; Ws[kq + 1][r] = wv.y;
            Ws[kq + 2][r] = wv.z; Ws[kq + 3][r] = wv.w;
        }
        __syncthreads();
        #pragma unroll
        for (int k = 0; k < 16; ++k) {
            float4 a = *(const float4*)&As[k][ty * 4];
            float4 b = *(const float4*)&Ws[k][tx * 4];
            float av[4] = {a.x, a.y, a.z, a.w};
            float bv[4] = {b.x, b.y, b.z, b.w};
            #pragma unroll
            for (int i = 0; i < 4; ++i)
                #pragma unroll
                for (int j = 0; j < 4; ++j)
                    acc[i][j] += av[i] * bv[j];
        }
        __syncthreads();
    }
    // epilogue: bias + exp, per-row partial over this 64-col block
    float rs[4] = {0.f, 0.f, 0.f, 0.f};
    #pragma unroll
    for (int i = 0; i < 4; ++i)
        #pragma unroll
        for (int j = 0; j < 4; ++j) {
            int c = cb + tx * 4 + j;
            if (c < vocab) {
                float bv = (c < split) ? bias[c] : biasx[c - split];
                rs[i] += expf(acc[i][j] + bv);
            }
        }
    #pragma unroll
    for (int i = 0; i < 4; ++i) red[tx][ty * 4 + i] = rs[i];
    __syncthreads();
    if (threadIdx.x < 64) {
        float s = 0.f;
        #pragma unroll
        for (int x = 0; x < 16; ++x) s += red[x][threadIdx.x];
        partial[(size_t)(rb + threadIdx.x) * nCB + blockIdx.x] = s;
    }
}

// ---------------------------------------------------------------------------
// Kernel 3: finalize — one wave per row; gathers target/cluster logits as
// dot products, sums partials, assembles NLL.
// ---------------------------------------------------------------------------
__global__ void pals_finalize(const float* __restrict__ H,
                              const int* __restrict__ target,
                              const float* __restrict__ w0, const float* __restrict__ b0,
                              const float* __restrict__ w1, const float* __restrict__ b1,
                              const float* __restrict__ w2, const float* __restrict__ b2,
                              const float* __restrict__ w3, const float* __restrict__ b3,
                              const float* __restrict__ cw, const float* __restrict__ cbv,
                              const float* __restrict__ pH,
                              const float* __restrict__ pT1,
                              const float* __restrict__ pT2,
                              const float* __restrict__ pT3,
                              float* __restrict__ out) {
    const int wave = threadIdx.x >> 6;
    const int lane = threadIdx.x & 63;
    const int row  = blockIdx.x * 4 + wave;
    if (row >= NROW) return;
    const int t = target[row];
    const float* Hrow = H + (size_t)row * LDH;

    // head log-sum-exp
    float s = 0.f;
    for (int c = lane; c < NB_H; c += 64) s += pH[(size_t)row * NB_H + c];
    #pragma unroll
    for (int off = 32; off; off >>= 1) s += __shfl_xor(s, off);
    const float logSh = logf(s);

    float nll;
    if (t < 20000) {
        const float* wr = w0 + (size_t)t * 1024;
        float d = 0.f;
        for (int k = lane * 4; k < 1024; k += 256) {
            float4 a = *(const float4*)(Hrow + k);
            float4 b = *(const float4*)(wr + k);
            d += a.x * b.x + a.y * b.y + a.z * b.z + a.w * b.w;
        }
        #pragma unroll
        for (int off = 32; off; off >>= 1) d += __shfl_xor(d, off);
        nll = -(d + b0[t] - logSh);
    } else {
        const int i  = (t - 20000) / 10000 + 1;        // 1..3
        const int ci = 3 - i;                           // head_lp[:, -i] quirk
        const float* cwr = cw + (size_t)ci * 1024;
        float d = 0.f;
        for (int k = lane * 4; k < 1024; k += 256) {
            float4 a = *(const float4*)(Hrow + k);
            float4 b = *(const float4*)(cwr + k);
            d += a.x * b.x + a.y * b.y + a.z * b.z + a.w * b.w;
        }
        #pragma unroll
        for (int off = 32; off; off >>= 1) d += __shfl_xor(d, off);
        const float logit_c = d + cbv[ci];

        const int dl   = 1024 >> (2 * i);               // 256, 64, 16
        const int hoff = (i == 1) ? 1024 : (i == 2) ? 1280 : 1344;
        const float* wi = (i == 1) ? w1 : (i == 2) ? w2 : w3;
        const float* bi = (i == 1) ? b1 : (i == 2) ? b2 : b3;
        const float* pT = (i == 1) ? pT1 : (i == 2) ? pT2 : pT3;
        const int tt = t - (20000 + (i - 1) * 10000);

        float dt = 0.f;
        const float* Hi = Hrow + hoff;
        for (int k = lane; k < dl; k += 64) dt += Hi[k] * wi[(size_t)tt * dl + k];
        #pragma unroll
        for (int off = 32; off; off >>= 1) dt += __shfl_xor(dt, off);

        float st = 0.f;
        for (int c = lane; c < NB_T; c += 64) st += pT[(size_t)row * NB_T + c];
        #pragma unroll
        for (int off = 32; off; off >>= 1) st += __shfl_xor(st, off);

        nll = -((logit_c - logSh) + (dt + bi[tt] - logf(st)));
    }
    if (lane == 0) out[row] = nll;
}

// ---------------------------------------------------------------------------
extern "C" void kernel_launch(void* const* d_in, const int* in_sizes, int n_in,
                              void* d_out, int out_size, void* d_ws, size_t ws_size,
                              hipStream_t stream) {
    const float* hidden = (const float*)d_in[0];
    const int*   target = (const int*)  d_in[1];
    const float* proj0  = (const float*)d_in[2];
    const float* w0     = (const float*)d_in[3];
    const float* b0     = (const float*)d_in[4];
    const float* proj1  = (const float*)d_in[5];
    const float* w1     = (const float*)d_in[6];
    const float* b1     = (const float*)d_in[7];
    const float* proj2  = (const float*)d_in[8];
    const float* w2     = (const float*)d_in[9];
    const float* b2     = (const float*)d_in[10];
    const float* proj3  = (const float*)d_in[11];
    const float* w3     = (const float*)d_in[12];
    const float* b3     = (const float*)d_in[13];
    const float* cw     = (const float*)d_in[14];
    const float* cbv    = (const float*)d_in[15];

    float* H   = (float*)d_ws;                      // [4096][1360]
    float* pH  = H   + (size_t)NROW * LDH;          // [4096][313]
    float* pT1 = pH  + (size_t)NROW * NB_H;         // [4096][157]
    float* pT2 = pT1 + (size_t)NROW * NB_T;
    float* pT3 = pT2 + (size_t)NROW * NB_T;

    dim3 blk(256);
    pals_proj_gemm<<<dim3(22, 64), blk, 0, stream>>>(hidden, proj0, proj1, proj2, proj3, H);

    // head: W = w0 (20000 rows), Wx = cluster_w (3 rows), vocab = 20003
    pals_logits_sumexp<<<dim3(NB_H, 64), blk, 0, stream>>>(
        H, 0, 1024, w0, cw, b0, cbv, 20000, 20003, pH, NB_H);
    // tails
    pals_logits_sumexp<<<dim3(NB_T, 64), blk, 0, stream>>>(
        H, 1024, 256, w1, nullptr, b1, nullptr, 10000, 10000, pT1, NB_T);
    pals_logits_sumexp<<<dim3(NB_T, 64), blk, 0, stream>>>(
        H, 1280, 64, w2, nullptr, b2, nullptr, 10000, 10000, pT2, NB_T);
    pals_logits_sumexp<<<dim3(NB_T, 64), blk, 0, stream>>>(
        H, 1344, 16, w3, nullptr, b3, nullptr, 10000, 10000, pT3, NB_T);

    pals_finalize<<<dim3(NROW / 4), blk, 0, stream>>>(
        H, target, w0, b0, w1, b1, w2, b2, w3, b3, cw, cbv,
        pH, pT1, pT2, pT3, (float*)d_out);
}

// Round 2
// 649.530 us; speedup vs baseline: 4.8287x; 4.8287x over previous
//
#include <hip/hip_runtime.h>
#include <hip/hip_bf16.h>
#include <math.h>

// Problem sizes (fixed)
#define NROW   4096
#define DPROJ  1024
#define LDHB   1408          // 1024 + 256 + 64 + 32(pad) rounded to 11*128
#define NB_H   157           // ceil(20096/128), head col-blocks (BN=128)
#define NB_T   79            // ceil(10112/128), tail col-blocks
#define HEAD_V 20003
#define TAIL_V 10000

typedef short short8 __attribute__((ext_vector_type(8)));
typedef float f32x4  __attribute__((ext_vector_type(4)));

__device__ __forceinline__ ushort f2bf(float f) {           // RNE f32 -> bf16
    unsigned u = __builtin_bit_cast(unsigned, f);
    return (ushort)((u + 0x7FFFu + ((u >> 16) & 1u)) >> 16);
}
__device__ __forceinline__ float bf2f(ushort u) {
    unsigned x = (unsigned)u << 16;
    return __builtin_bit_cast(float, x);
}

#define GLOAD16(gp, lp) __builtin_amdgcn_global_load_lds(                     \
    (const __attribute__((address_space(1))) void*)(gp),                      \
    (__attribute__((address_space(3))) void*)(lp), 16, 0, 0)

// ---------------------------------------------------------------------------
// cast hidden f32 -> bf16
// ---------------------------------------------------------------------------
__global__ void cast_hidden_k(const float* __restrict__ h, ushort* __restrict__ hb) {
    int i = (blockIdx.x * 256 + threadIdx.x) * 4;
    float4 v = *(const float4*)(h + i);
    ushort4 o = {f2bf(v.x), f2bf(v.y), f2bf(v.z), f2bf(v.w)};
    *(ushort4*)(hb + i) = o;
}

// ---------------------------------------------------------------------------
// transpose-cast proj concat -> pbT [1408][1024] bf16 (rows = out col, K-contig)
// ---------------------------------------------------------------------------
__global__ void cast_transpose_proj(const float* __restrict__ p0, const float* __restrict__ p1,
                                    const float* __restrict__ p2, const float* __restrict__ p3,
                                    ushort* __restrict__ pbT) {
    __shared__ float tile[64][65];
    const int t  = threadIdx.x;
    const int kb = blockIdx.x * 64;    // k tile, 16 blocks
    const int cb = blockIdx.y * 64;    // c tile, 22 blocks
    for (int p = 0; p < 4; ++p) {
        int kl = p * 16 + (t >> 4);
        int c4 = (t & 15) * 4;
        int k  = kb + kl;
        for (int j = 0; j < 4; ++j) {
            int c = cb + c4 + j;
            float v = 0.f;
            if      (c < 1024) v = p0[(size_t)k * 1024 + c];
            else if (c < 1280) v = p1[(size_t)k * 256  + (c - 1024)];
            else if (c < 1344) v = p2[(size_t)k * 64   + (c - 1280)];
            else if (c < 1360) v = p3[(size_t)k * 16   + (c - 1344)];
            tile[kl][c4 + j] = v;
        }
    }
    __syncthreads();
    for (int p = 0; p < 4; ++p) {
        int cl = p * 16 + (t >> 4);
        int k4 = (t & 15) * 4;
        ushort4 o = {f2bf(tile[k4 + 0][cl]), f2bf(tile[k4 + 1][cl]),
                     f2bf(tile[k4 + 2][cl]), f2bf(tile[k4 + 3][cl])};
        *(ushort4*)(pbT + (size_t)(cb + cl) * 1024 + kb + k4) = o;
    }
}

// ---------------------------------------------------------------------------
// Proj GEMM: Hb[4096][1408] = hb[4096][1024] @ pbT^T   (both bf16, MFMA)
// 128x128 tile, BK=32, 4 waves, global_load_lds both operands.
// ---------------------------------------------------------------------------
__global__ __launch_bounds__(256) void proj_gemm_mfma(const ushort* __restrict__ A,
                                                      const ushort* __restrict__ B,
                                                      ushort* __restrict__ C) {
    __shared__ ushort As[128 * 32];
    __shared__ ushort Bs[128 * 32];
    const int t  = threadIdx.x;
    const int wv = t >> 6, l = t & 63, lr = l & 15, lh = l >> 4;
    const int wr = wv >> 1, wc = wv & 1;
    const int rb = blockIdx.x * 128, cb = blockIdx.y * 128;
    f32x4 acc[4][4] = {};
    for (int k0 = 0; k0 < DPROJ; k0 += 32) {
        __syncthreads();
        #pragma unroll
        for (int is = 0; is < 2; ++is) {
            int rr = (t >> 2) + is * 64;
            GLOAD16(A + (size_t)(rb + rr) * DPROJ + k0 + (t & 3) * 8,
                    (char*)As + wv * 1024 + is * 4096);
            GLOAD16(B + (size_t)(cb + rr) * DPROJ + k0 + (t & 3) * 8,
                    (char*)Bs + wv * 1024 + is * 4096);
        }
        __syncthreads();
        short8 af[4], bf[4];
        #pragma unroll
        for (int m = 0; m < 4; ++m)
            af[m] = *(const short8*)(As + (wr * 64 + m * 16 + lr) * 32 + lh * 8);
        #pragma unroll
        for (int n = 0; n < 4; ++n)
            bf[n] = *(const short8*)(Bs + (wc * 64 + n * 16 + lr) * 32 + lh * 8);
        #pragma unroll
        for (int m = 0; m < 4; ++m)
            #pragma unroll
            for (int n = 0; n < 4; ++n)
                acc[m][n] = __builtin_amdgcn_mfma_f32_16x16x32_bf16(af[m], bf[n], acc[m][n], 0, 0, 0);
    }
    #pragma unroll
    for (int m = 0; m < 4; ++m)
        #pragma unroll
        for (int n = 0; n < 4; ++n)
            #pragma unroll
            for (int r = 0; r < 4; ++r) {
                int rl = wr * 64 + m * 16 + lh * 4 + r;
                int cl = wc * 64 + n * 16 + lr;
                C[(size_t)(rb + rl) * LDHB + cb + cl] = f2bf(acc[m][n][r]);
            }
}

// ---------------------------------------------------------------------------
// Logits GEMM + sum-exp partials. A = Hb[:, aoff:aoff+K] bf16 (async LDS);
// B = fp32 weight rows (reg-staged + cast). Per-row partial per 128-col block.
// ---------------------------------------------------------------------------
template<int K>
__global__ __launch_bounds__(256) void gemm_sumexp(
        const ushort* __restrict__ A, int aoff,
        const float* __restrict__ W, const float* __restrict__ Wx,
        int strideB, int splitB, int vocab, int krealB,
        const float* __restrict__ bias, const float* __restrict__ biasx,
        float* __restrict__ partial, int nCB) {
    __shared__ ushort As[128 * 32];
    __shared__ ushort Bs[128 * 32];
    __shared__ float  red[2][128];
    const int t  = threadIdx.x;
    const int wv = t >> 6, l = t & 63, lr = l & 15, lh = l >> 4;
    const int wr = wv >> 1, wc = wv & 1;
    const int rb = blockIdx.x * 128, cb = blockIdx.y * 128;
    f32x4 acc[4][4] = {};
    for (int k0 = 0; k0 < K; k0 += 32) {
        __syncthreads();
        #pragma unroll
        for (int is = 0; is < 2; ++is) {
            int rr = (t >> 2) + is * 64;
            GLOAD16(A + (size_t)(rb + rr) * LDHB + aoff + k0 + (t & 3) * 8,
                    (char*)As + wv * 1024 + is * 4096);
            // B: fp32 -> bf16 reg-stage
            int gc   = cb + rr;
            int koff = k0 + (t & 3) * 8;
            float4 v0 = {0.f, 0.f, 0.f, 0.f}, v1 = {0.f, 0.f, 0.f, 0.f};
            if (gc < vocab && koff < krealB) {
                const float* srow = (gc < splitB) ? (W + (size_t)gc * strideB)
                                                  : (Wx + (size_t)(gc - splitB) * strideB);
                v0 = *(const float4*)(srow + koff);
                v1 = *(const float4*)(srow + koff + 4);
            }
            union { ushort u[8]; uint4 q; } pk;
            pk.u[0] = f2bf(v0.x); pk.u[1] = f2bf(v0.y); pk.u[2] = f2bf(v0.z); pk.u[3] = f2bf(v0.w);
            pk.u[4] = f2bf(v1.x); pk.u[5] = f2bf(v1.y); pk.u[6] = f2bf(v1.z); pk.u[7] = f2bf(v1.w);
            *(uint4*)(Bs + rr * 32 + (t & 3) * 8) = pk.q;
        }
        __syncthreads();
        short8 af[4], bf[4];
        #pragma unroll
        for (int m = 0; m < 4; ++m)
            af[m] = *(const short8*)(As + (wr * 64 + m * 16 + lr) * 32 + lh * 8);
        #pragma unroll
        for (int n = 0; n < 4; ++n)
            bf[n] = *(const short8*)(Bs + (wc * 64 + n * 16 + lr) * 32 + lh * 8);
        #pragma unroll
        for (int m = 0; m < 4; ++m)
            #pragma unroll
            for (int n = 0; n < 4; ++n)
                acc[m][n] = __builtin_amdgcn_mfma_f32_16x16x32_bf16(af[m], bf[n], acc[m][n], 0, 0, 0);
    }
    // epilogue: exp(logit + bias), row-sum over this block's 128 cols
    float rs[4][4];
    #pragma unroll
    for (int m = 0; m < 4; ++m)
        #pragma unroll
        for (int r = 0; r < 4; ++r) {
            float s = 0.f;
            #pragma unroll
            for (int n = 0; n < 4; ++n) {
                int col = cb + wc * 64 + n * 16 + lr;
                if (col < vocab) {
                    float bv = (col < splitB) ? bias[col] : biasx[col - splitB];
                    s += expf(acc[m][n][r] + bv);
                }
            }
            rs[m][r] = s;
        }
    #pragma unroll
    for (int m = 0; m < 4; ++m)
        #pragma unroll
        for (int r = 0; r < 4; ++r) {
            #pragma unroll
            for (int off = 1; off < 16; off <<= 1)
                rs[m][r] += __shfl_xor(rs[m][r], off);
            if (lr == 0) red[wc][wr * 64 + m * 16 + lh * 4 + r] = rs[m][r];
        }
    __syncthreads();
    if (t < 128)
        partial[(size_t)(rb + t) * nCB + blockIdx.y] = red[0][t] + red[1][t];
}

// ---------------------------------------------------------------------------
// Finalize: one wave per row — gather target/cluster logits, assemble NLL.
// ---------------------------------------------------------------------------
__global__ void pals_finalize(const ushort* __restrict__ Hb,
                              const int* __restrict__ target,
                              const float* __restrict__ w0, const float* __restrict__ b0,
                              const float* __restrict__ w1, const float* __restrict__ b1,
                              const float* __restrict__ w2, const float* __restrict__ b2,
                              const float* __restrict__ w3, const float* __restrict__ b3,
                              const float* __restrict__ cw, const float* __restrict__ cbv,
                              const float* __restrict__ pH,
                              const float* __restrict__ pT1,
                              const float* __restrict__ pT2,
                              const float* __restrict__ pT3,
                              float* __restrict__ out) {
    const int wave = threadIdx.x >> 6;
    const int lane = threadIdx.x & 63;
    const int row  = blockIdx.x * 4 + wave;
    if (row >= NROW) return;
    const int t = target[row];
    const ushort* Hrow = Hb + (size_t)row * LDHB;

    float s = 0.f;
    for (int c = lane; c < NB_H; c += 64) s += pH[(size_t)row * NB_H + c];
    #pragma unroll
    for (int off = 32; off; off >>= 1) s += __shfl_xor(s, off);
    const float logSh = logf(s);

    float nll;
    if (t < 20000) {
        const float* wr0 = w0 + (size_t)t * 1024;
        float d = 0.f;
        for (int k = lane * 4; k < 1024; k += 256) {
            ushort4 a = *(const ushort4*)(Hrow + k);
            float4  b = *(const float4*)(wr0 + k);
            d += bf2f(a.x) * b.x + bf2f(a.y) * b.y + bf2f(a.z) * b.z + bf2f(a.w) * b.w;
        }
        #pragma unroll
        for (int off = 32; off; off >>= 1) d += __shfl_xor(d, off);
        nll = -(d + b0[t] - logSh);
    } else {
        const int i  = (t - 20000) / 10000 + 1;        // 1..3
        const int ci = 3 - i;                           // head_lp[:, -i] quirk
        const float* cwr = cw + (size_t)ci * 1024;
        float d = 0.f;
        for (int k = lane * 4; k < 1024; k += 256) {
            ushort4 a = *(const ushort4*)(Hrow + k);
            float4  b = *(const float4*)(cwr + k);
            d += bf2f(a.x) * b.x + bf2f(a.y) * b.y + bf2f(a.z) * b.z + bf2f(a.w) * b.w;
        }
        #pragma unroll
        for (int off = 32; off; off >>= 1) d += __shfl_xor(d, off);
        const float logit_c = d + cbv[ci];

        const int dl   = 1024 >> (2 * i);               // 256, 64, 16
        const int hoff = (i == 1) ? 1024 : (i == 2) ? 1280 : 1344;
        const float* wi = (i == 1) ? w1 : (i == 2) ? w2 : w3;
        const float* bi = (i == 1) ? b1 : (i == 2) ? b2 : b3;
        const float* pT = (i == 1) ? pT1 : (i == 2) ? pT2 : pT3;
        const int tt = t - (20000 + (i - 1) * 10000);

        float dt = 0.f;
        const ushort* Hi = Hrow + hoff;
        for (int k = lane; k < dl; k += 64) dt += bf2f(Hi[k]) * wi[(size_t)tt * dl + k];
        #pragma unroll
        for (int off = 32; off; off >>= 1) dt += __shfl_xor(dt, off);

        float st = 0.f;
        for (int c = lane; c < NB_T; c += 64) st += pT[(size_t)row * NB_T + c];
        #pragma unroll
        for (int off = 32; off; off >>= 1) st += __shfl_xor(st, off);

        nll = -((logit_c - logSh) + (dt + bi[tt] - logf(st)));
    }
    if (lane == 0) out[row] = nll;
}

// ---------------------------------------------------------------------------
extern "C" void kernel_launch(void* const* d_in, const int* in_sizes, int n_in,
                              void* d_out, int out_size, void* d_ws, size_t ws_size,
                              hipStream_t stream) {
    const float* hidden = (const float*)d_in[0];
    const int*   target = (const int*)  d_in[1];
    const float* proj0  = (const float*)d_in[2];
    const float* w0     = (const float*)d_in[3];
    const float* b0     = (const float*)d_in[4];
    const float* proj1  = (const float*)d_in[5];
    const float* w1     = (const float*)d_in[6];
    const float* b1     = (const float*)d_in[7];
    const float* proj2  = (const float*)d_in[8];
    const float* w2     = (const float*)d_in[9];
    const float* b2     = (const float*)d_in[10];
    const float* proj3  = (const float*)d_in[11];
    const float* w3     = (const float*)d_in[12];
    const float* b3     = (const float*)d_in[13];
    const float* cw     = (const float*)d_in[14];
    const float* cbv    = (const float*)d_in[15];

    ushort* hb  = (ushort*)d_ws;                         // [4096][1024] bf16
    ushort* pbT = hb  + (size_t)NROW * DPROJ;            // [1408][1024] bf16
    ushort* Hb  = pbT + (size_t)LDHB * DPROJ;            // [4096][1408] bf16
    float*  pH  = (float*)(Hb + (size_t)NROW * LDHB);    // [4096][157]
    float*  pT1 = pH  + (size_t)NROW * NB_H;             // [4096][79]
    float*  pT2 = pT1 + (size_t)NROW * NB_T;
    float*  pT3 = pT2 + (size_t)NROW * NB_T;

    dim3 blk(256);
    cast_hidden_k<<<dim3(NROW * DPROJ / 1024), blk, 0, stream>>>(hidden, hb);
    cast_transpose_proj<<<dim3(16, 22), blk, 0, stream>>>(proj0, proj1, proj2, proj3, pbT);
    proj_gemm_mfma<<<dim3(32, 11), blk, 0, stream>>>(hb, pbT, Hb);

    // head: 20000 w0 rows + 3 cluster rows, vocab 20003
    gemm_sumexp<1024><<<dim3(32, NB_H), blk, 0, stream>>>(
        Hb, 0, w0, cw, 1024, 20000, HEAD_V, 1024, b0, cbv, pH, NB_H);
    // tails
    gemm_sumexp<256><<<dim3(32, NB_T), blk, 0, stream>>>(
        Hb, 1024, w1, nullptr, 256, TAIL_V, TAIL_V, 256, b1, nullptr, pT1, NB_T);
    gemm_sumexp<64><<<dim3(32, NB_T), blk, 0, stream>>>(
        Hb, 1280, w2, nullptr, 64, TAIL_V, TAIL_V, 64, b2, nullptr, pT2, NB_T);
    gemm_sumexp<32><<<dim3(32, NB_T), blk, 0, stream>>>(
        Hb, 1344, w3, nullptr, 16, TAIL_V, TAIL_V, 16, b3, nullptr, pT3, NB_T);

    pals_finalize<<<dim3(NROW / 4), blk, 0, stream>>>(
        Hb, target, w0, b0, w1, b1, w2, b2, w3, b3, cw, cbv,
        pH, pT1, pT2, pT3, (float*)d_out);
}

// Round 3
// 563.563 us; speedup vs baseline: 5.5653x; 1.1525x over previous
//
#include <hip/hip_runtime.h>
#include <hip/hip_bf16.h>
#include <math.h>

// Problem sizes (fixed)
#define NROW   4096
#define DPROJ  1024
#define LDHB   1408          // 1024 + 256 + 64 + 32(pad for K=32 tail) + pad to 11*128
#define NB_H   157           // ceil(20003/128)
#define NB_T   79            // ceil(10000/128)
#define HEAD_V 20003
#define TAIL_V 10000
#define HEAD_VP 20096        // 157*128
#define TAIL_VP 10112        // 79*128

typedef short short8 __attribute__((ext_vector_type(8)));
typedef float f32x4  __attribute__((ext_vector_type(4)));

__device__ __forceinline__ ushort f2bf(float f) {           // RNE f32 -> bf16
    unsigned u = __builtin_bit_cast(unsigned, f);
    return (ushort)((u + 0x7FFFu + ((u >> 16) & 1u)) >> 16);
}
__device__ __forceinline__ float bf2f(ushort u) {
    unsigned x = (unsigned)u << 16;
    return __builtin_bit_cast(float, x);
}

#define GLOAD16(gp, lp) __builtin_amdgcn_global_load_lds(                     \
    (const __attribute__((address_space(1))) void*)(gp),                      \
    (__attribute__((address_space(3))) void*)(lp), 16, 0, 0)

// ---------------------------------------------------------------------------
// cast hidden f32 -> bf16  (4096x1024)
// ---------------------------------------------------------------------------
__global__ void cast_hidden_k(const float* __restrict__ h, ushort* __restrict__ hb) {
    int i = (blockIdx.x * 256 + threadIdx.x) * 4;
    float4 v = *(const float4*)(h + i);
    ushort4 o = {f2bf(v.x), f2bf(v.y), f2bf(v.z), f2bf(v.w)};
    *(ushort4*)(hb + i) = o;
}

// ---------------------------------------------------------------------------
// transpose-cast proj concat -> pbT [1408][1024] bf16 (row = out col, K-contig)
// ---------------------------------------------------------------------------
__global__ void cast_transpose_proj(const float* __restrict__ p0, const float* __restrict__ p1,
                                    const float* __restrict__ p2, const float* __restrict__ p3,
                                    ushort* __restrict__ pbT) {
    __shared__ float tile[64][65];
    const int t  = threadIdx.x;
    const int kb = blockIdx.x * 64;    // k tile, 16 blocks
    const int cb = blockIdx.y * 64;    // c tile, 22 blocks
    for (int p = 0; p < 4; ++p) {
        int kl = p * 16 + (t >> 4);
        int c4 = (t & 15) * 4;
        int k  = kb + kl;
        for (int j = 0; j < 4; ++j) {
            int c = cb + c4 + j;
            float v = 0.f;
            if      (c < 1024) v = p0[(size_t)k * 1024 + c];
            else if (c < 1280) v = p1[(size_t)k * 256  + (c - 1024)];
            else if (c < 1344) v = p2[(size_t)k * 64   + (c - 1280)];
            else if (c < 1360) v = p3[(size_t)k * 16   + (c - 1344)];
            tile[kl][c4 + j] = v;
        }
    }
    __syncthreads();
    for (int p = 0; p < 4; ++p) {
        int cl = p * 16 + (t >> 4);
        int k4 = (t & 15) * 4;
        ushort4 o = {f2bf(tile[k4 + 0][cl]), f2bf(tile[k4 + 1][cl]),
                     f2bf(tile[k4 + 2][cl]), f2bf(tile[k4 + 3][cl])};
        *(ushort4*)(pbT + (size_t)(cb + cl) * 1024 + kb + k4) = o;
    }
}

// ---------------------------------------------------------------------------
// cast head weight: [w0 (20000) | cluster_w (3) | zeros] -> WH [20096][1024] bf16
// one block per row, 256 thr x 4 elems
// ---------------------------------------------------------------------------
__global__ void cast_head_w(const float* __restrict__ w0, const float* __restrict__ cw,
                            ushort* __restrict__ dst) {
    const int row = blockIdx.x;
    const int c   = threadIdx.x * 4;
    float4 v = {0.f, 0.f, 0.f, 0.f};
    if (row < 20000)      v = *(const float4*)(w0 + (size_t)row * 1024 + c);
    else if (row < 20003) v = *(const float4*)(cw + (size_t)(row - 20000) * 1024 + c);
    ushort4 o = {f2bf(v.x), f2bf(v.y), f2bf(v.z), f2bf(v.w)};
    *(ushort4*)(dst + (size_t)row * 1024 + c) = o;
}

// ---------------------------------------------------------------------------
// cast tail weight with row pad + K pad: src [rows_real][kin] -> dst [TAIL_VP][KOUT]
// ---------------------------------------------------------------------------
template<int KOUT>
__global__ void cast_tail_w(const float* __restrict__ src, ushort* __restrict__ dst,
                            int rows_real, int kin) {
    int idx = blockIdx.x * 256 + threadIdx.x;
    const int n = TAIL_VP * KOUT;
    if (idx >= n) return;
    int r = idx / KOUT, k = idx - r * KOUT;
    float v = (r < rows_real && k < kin) ? src[(size_t)r * kin + k] : 0.f;
    dst[idx] = f2bf(v);
}

// ---------------------------------------------------------------------------
// Proj GEMM: Hb[4096][1408] = hb[4096][1024] @ pbT^T   (both bf16, MFMA)
// 128x128 tile, BK=32, 4 waves, global_load_lds both operands.
// ---------------------------------------------------------------------------
__global__ __launch_bounds__(256) void proj_gemm_mfma(const ushort* __restrict__ A,
                                                      const ushort* __restrict__ B,
                                                      ushort* __restrict__ C) {
    __shared__ ushort As[128 * 32];
    __shared__ ushort Bs[128 * 32];
    const int t  = threadIdx.x;
    const int wv = t >> 6, l = t & 63, lr = l & 15, lh = l >> 4;
    const int wr = wv >> 1, wc = wv & 1;
    const int rb = blockIdx.x * 128, cb = blockIdx.y * 128;
    f32x4 acc[4][4] = {};
    for (int k0 = 0; k0 < DPROJ; k0 += 32) {
        __syncthreads();
        #pragma unroll
        for (int is = 0; is < 2; ++is) {
            int rr = (t >> 2) + is * 64;
            GLOAD16(A + (size_t)(rb + rr) * DPROJ + k0 + (t & 3) * 8,
                    (char*)As + wv * 1024 + is * 4096);
            GLOAD16(B + (size_t)(cb + rr) * DPROJ + k0 + (t & 3) * 8,
                    (char*)Bs + wv * 1024 + is * 4096);
        }
        __syncthreads();
        short8 af[4], bf[4];
        #pragma unroll
        for (int m = 0; m < 4; ++m)
            af[m] = *(const short8*)(As + (wr * 64 + m * 16 + lr) * 32 + lh * 8);
        #pragma unroll
        for (int n = 0; n < 4; ++n)
            bf[n] = *(const short8*)(Bs + (wc * 64 + n * 16 + lr) * 32 + lh * 8);
        #pragma unroll
        for (int m = 0; m < 4; ++m)
            #pragma unroll
            for (int n = 0; n < 4; ++n)
                acc[m][n] = __builtin_amdgcn_mfma_f32_16x16x32_bf16(af[m], bf[n], acc[m][n], 0, 0, 0);
    }
    #pragma unroll
    for (int m = 0; m < 4; ++m)
        #pragma unroll
        for (int n = 0; n < 4; ++n)
            #pragma unroll
            for (int r = 0; r < 4; ++r) {
                int rl = wr * 64 + m * 16 + lh * 4 + r;
                int cl = wc * 64 + n * 16 + lr;
                C[(size_t)(rb + rl) * LDHB + cb + cl] = f2bf(acc[m][n][r]);
            }
}

// ---------------------------------------------------------------------------
// Pure-bf16 logits GEMM + sum-exp partials (m97 structure).
// A: bf16, row stride LDHB, pre-offset to the cluster's column window.
// B: bf16 [vocab_padded][K], zero-padded. Epilogue masks col >= vocab.
// ---------------------------------------------------------------------------
template<int K>
__global__ __launch_bounds__(256) void gemm_sumexp_bf(
        const ushort* __restrict__ A,
        const ushort* __restrict__ B,
        const float* __restrict__ bias, const float* __restrict__ biasx,
        int splitB, int vocab,
        float* __restrict__ partial, int nCB) {
    __shared__ ushort As[128 * 32];
    __shared__ ushort Bs[128 * 32];
    __shared__ float  red[2][128];
    const int t  = threadIdx.x;
    const int wv = t >> 6, l = t & 63, lr = l & 15, lh = l >> 4;
    const int wr = wv >> 1, wc = wv & 1;
    const int rb = blockIdx.x * 128, cb = blockIdx.y * 128;
    f32x4 acc[4][4] = {};
    for (int k0 = 0; k0 < K; k0 += 32) {
        __syncthreads();
        #pragma unroll
        for (int is = 0; is < 2; ++is) {
            int rr = (t >> 2) + is * 64;
            GLOAD16(A + (size_t)(rb + rr) * LDHB + k0 + (t & 3) * 8,
                    (char*)As + wv * 1024 + is * 4096);
            GLOAD16(B + (size_t)(cb + rr) * K + k0 + (t & 3) * 8,
                    (char*)Bs + wv * 1024 + is * 4096);
        }
        __syncthreads();
        short8 af[4], bf[4];
        #pragma unroll
        for (int m = 0; m < 4; ++m)
            af[m] = *(const short8*)(As + (wr * 64 + m * 16 + lr) * 32 + lh * 8);
        #pragma unroll
        for (int n = 0; n < 4; ++n)
            bf[n] = *(const short8*)(Bs + (wc * 64 + n * 16 + lr) * 32 + lh * 8);
        #pragma unroll
        for (int m = 0; m < 4; ++m)
            #pragma unroll
            for (int n = 0; n < 4; ++n)
                acc[m][n] = __builtin_amdgcn_mfma_f32_16x16x32_bf16(af[m], bf[n], acc[m][n], 0, 0, 0);
    }
    // epilogue: exp(logit + bias), per-row partial over this 128-col block
    float rs[4][4];
    #pragma unroll
    for (int m = 0; m < 4; ++m)
        #pragma unroll
        for (int r = 0; r < 4; ++r) {
            float s = 0.f;
            #pragma unroll
            for (int n = 0; n < 4; ++n) {
                int col = cb + wc * 64 + n * 16 + lr;
                if (col < vocab) {
                    float bv = (col < splitB) ? bias[col] : biasx[col - splitB];
                    s += expf(acc[m][n][r] + bv);
                }
            }
            rs[m][r] = s;
        }
    #pragma unroll
    for (int m = 0; m < 4; ++m)
        #pragma unroll
        for (int r = 0; r < 4; ++r) {
            #pragma unroll
            for (int off = 1; off < 16; off <<= 1)
                rs[m][r] += __shfl_xor(rs[m][r], off);
            if (lr == 0) red[wc][wr * 64 + m * 16 + lh * 4 + r] = rs[m][r];
        }
    __syncthreads();
    if (t < 128)
        partial[(size_t)(rb + t) * nCB + blockIdx.y] = red[0][t] + red[1][t];
}

// ---------------------------------------------------------------------------
// Finalize: one wave per row — gather target/cluster logits, assemble NLL.
// ---------------------------------------------------------------------------
__global__ void pals_finalize(const ushort* __restrict__ Hb,
                              const int* __restrict__ target,
                              const float* __restrict__ w0, const float* __restrict__ b0,
                              const float* __restrict__ w1, const float* __restrict__ b1,
                              const float* __restrict__ w2, const float* __restrict__ b2,
                              const float* __restrict__ w3, const float* __restrict__ b3,
                              const float* __restrict__ cw, const float* __restrict__ cbv,
                              const float* __restrict__ pH,
                              const float* __restrict__ pT1,
                              const float* __restrict__ pT2,
                              const float* __restrict__ pT3,
                              float* __restrict__ out) {
    const int wave = threadIdx.x >> 6;
    const int lane = threadIdx.x & 63;
    const int row  = blockIdx.x * 4 + wave;
    if (row >= NROW) return;
    const int t = target[row];
    const ushort* Hrow = Hb + (size_t)row * LDHB;

    float s = 0.f;
    for (int c = lane; c < NB_H; c += 64) s += pH[(size_t)row * NB_H + c];
    #pragma unroll
    for (int off = 32; off; off >>= 1) s += __shfl_xor(s, off);
    const float logSh = logf(s);

    float nll;
    if (t < 20000) {
        const float* wr0 = w0 + (size_t)t * 1024;
        float d = 0.f;
        for (int k = lane * 4; k < 1024; k += 256) {
            ushort4 a = *(const ushort4*)(Hrow + k);
            float4  b = *(const float4*)(wr0 + k);
            d += bf2f(a.x) * b.x + bf2f(a.y) * b.y + bf2f(a.z) * b.z + bf2f(a.w) * b.w;
        }
        #pragma unroll
        for (int off = 32; off; off >>= 1) d += __shfl_xor(d, off);
        nll = -(d + b0[t] - logSh);
    } else {
        const int i  = (t - 20000) / 10000 + 1;        // 1..3
        const int ci = 3 - i;                           // head_lp[:, -i] quirk
        const float* cwr = cw + (size_t)ci * 1024;
        float d = 0.f;
        for (int k = lane * 4; k < 1024; k += 256) {
            ushort4 a = *(const ushort4*)(Hrow + k);
            float4  b = *(const float4*)(cwr + k);
            d += bf2f(a.x) * b.x + bf2f(a.y) * b.y + bf2f(a.z) * b.z + bf2f(a.w) * b.w;
        }
        #pragma unroll
        for (int off = 32; off; off >>= 1) d += __shfl_xor(d, off);
        const float logit_c = d + cbv[ci];

        const int dl   = 1024 >> (2 * i);               // 256, 64, 16
        const int hoff = (i == 1) ? 1024 : (i == 2) ? 1280 : 1344;
        const float* wi = (i == 1) ? w1 : (i == 2) ? w2 : w3;
        const float* bi = (i == 1) ? b1 : (i == 2) ? b2 : b3;
        const float* pT = (i == 1) ? pT1 : (i == 2) ? pT2 : pT3;
        const int tt = t - (20000 + (i - 1) * 10000);

        float dt = 0.f;
        const ushort* Hi = Hrow + hoff;
        for (int k = lane; k < dl; k += 64) dt += bf2f(Hi[k]) * wi[(size_t)tt * dl + k];
        #pragma unroll
        for (int off = 32; off; off >>= 1) dt += __shfl_xor(dt, off);

        float st = 0.f;
        for (int c = lane; c < NB_T; c += 64) st += pT[(size_t)row * NB_T + c];
        #pragma unroll
        for (int off = 32; off; off >>= 1) st += __shfl_xor(st, off);

        nll = -((logit_c - logSh) + (dt + bi[tt] - logf(st)));
    }
    if (lane == 0) out[row] = nll;
}

// ---------------------------------------------------------------------------
extern "C" void kernel_launch(void* const* d_in, const int* in_sizes, int n_in,
                              void* d_out, int out_size, void* d_ws, size_t ws_size,
                              hipStream_t stream) {
    const float* hidden = (const float*)d_in[0];
    const int*   target = (const int*)  d_in[1];
    const float* proj0  = (const float*)d_in[2];
    const float* w0     = (const float*)d_in[3];
    const float* b0     = (const float*)d_in[4];
    const float* proj1  = (const float*)d_in[5];
    const float* w1     = (const float*)d_in[6];
    const float* b1     = (const float*)d_in[7];
    const float* proj2  = (const float*)d_in[8];
    const float* w2     = (const float*)d_in[9];
    const float* b2     = (const float*)d_in[10];
    const float* proj3  = (const float*)d_in[11];
    const float* w3     = (const float*)d_in[12];
    const float* b3     = (const float*)d_in[13];
    const float* cw     = (const float*)d_in[14];
    const float* cbv    = (const float*)d_in[15];

    ushort* hb  = (ushort*)d_ws;                         // [4096][1024]  8.4 MB
    ushort* pbT = hb  + (size_t)NROW * DPROJ;            // [1408][1024]  2.9 MB
    ushort* Hb  = pbT + (size_t)LDHB * DPROJ;            // [4096][1408] 11.5 MB
    ushort* WH  = Hb  + (size_t)NROW * LDHB;             // [20096][1024] 41.2 MB
    ushort* WT1 = WH  + (size_t)HEAD_VP * 1024;          // [10112][256]  5.2 MB
    ushort* WT2 = WT1 + (size_t)TAIL_VP * 256;           // [10112][64]   1.3 MB
    ushort* WT3 = WT2 + (size_t)TAIL_VP * 64;            // [10112][32]   0.7 MB
    float*  pH  = (float*)(WT3 + (size_t)TAIL_VP * 32);  // [4096][157]
    float*  pT1 = pH  + (size_t)NROW * NB_H;             // [4096][79]
    float*  pT2 = pT1 + (size_t)NROW * NB_T;
    float*  pT3 = pT2 + (size_t)NROW * NB_T;

    dim3 blk(256);
    cast_hidden_k<<<dim3(NROW * DPROJ / 1024), blk, 0, stream>>>(hidden, hb);
    cast_transpose_proj<<<dim3(16, 22), blk, 0, stream>>>(proj0, proj1, proj2, proj3, pbT);
    cast_head_w<<<dim3(HEAD_VP), blk, 0, stream>>>(w0, cw, WH);
    cast_tail_w<256><<<dim3((TAIL_VP * 256 + 255) / 256), blk, 0, stream>>>(w1, WT1, TAIL_V, 256);
    cast_tail_w<64><<<dim3((TAIL_VP * 64 + 255) / 256), blk, 0, stream>>>(w2, WT2, TAIL_V, 64);
    cast_tail_w<32><<<dim3((TAIL_VP * 32 + 255) / 256), blk, 0, stream>>>(w3, WT3, TAIL_V, 16);

    proj_gemm_mfma<<<dim3(32, 11), blk, 0, stream>>>(hb, pbT, Hb);

    // head: 20000 w0 rows + 3 cluster rows, vocab 20003
    gemm_sumexp_bf<1024><<<dim3(32, NB_H), blk, 0, stream>>>(
        Hb, WH, b0, cbv, 20000, HEAD_V, pH, NB_H);
    // tails (A pre-offset into Hb's column window)
    gemm_sumexp_bf<256><<<dim3(32, NB_T), blk, 0, stream>>>(
        Hb + 1024, WT1, b1, nullptr, TAIL_V, TAIL_V, pT1, NB_T);
    gemm_sumexp_bf<64><<<dim3(32, NB_T), blk, 0, stream>>>(
        Hb + 1280, WT2, b2, nullptr, TAIL_V, TAIL_V, pT2, NB_T);
    gemm_sumexp_bf<32><<<dim3(32, NB_T), blk, 0, stream>>>(
        Hb + 1344, WT3, b3, nullptr, TAIL_V, TAIL_V, pT3, NB_T);

    pals_finalize<<<dim3(NROW / 4), blk, 0, stream>>>(
        Hb, target, w0, b0, w1, b1, w2, b2, w3, b3, cw, cbv,
        pH, pT1, pT2, pT3, (float*)d_out);
}